// Round 11
// baseline (1256.120 us; speedup 1.0000x reference)
//
#include <hip/hip_runtime.h>
#include <hip/hip_bf16.h>

#define BATCH  4096
#define NCC    64
#define HDIM   256
#define G3     768
#define NROW   (BATCH*NCC)   // 262144
#define NK     20
#define LOG2PI 1.8378770664093453f

typedef __attribute__((ext_vector_type(8))) short bf16x8;
typedef __attribute__((ext_vector_type(4))) float f32x4;

__device__ __forceinline__ float sigm(float x) { return 1.0f/(1.0f + __expf(-x)); }
__device__ __forceinline__ float tanh_fast(float x) { return 1.0f - 2.0f/(__expf(2.0f*x) + 1.0f); }
__device__ __forceinline__ unsigned short f2bf(float x) {
  __hip_bfloat16 h = __float2bfloat16(x);
  return __builtin_bit_cast(unsigned short, h);
}
__device__ __forceinline__ int swz(int r) { return (r & 7) ^ ((r & 8) >> 2); }

// Async global->LDS, 16B per lane. LDS dest is WAVE-UNIFORM base + lane*16.
typedef const __attribute__((address_space(1))) unsigned int glb_u32;
typedef __attribute__((address_space(3))) unsigned int lds_u32;
__device__ __forceinline__ void gload16(const unsigned short* g, unsigned short* l) {
  __builtin_amdgcn_global_load_lds((glb_u32*)g, (lds_u32*)l, 16, 0, 0);
}

// MFMA via inline asm: B operand constrained to AGPR ("a") or VGPR ("v").
#define MFMA_BA(d, a, b) \
  asm("v_mfma_f32_16x16x32_bf16 %0, %1, %2, %0" : "+v"(d) : "v"(a), "a"(b))
#define MFMA_BV(d, a, b) \
  asm("v_mfma_f32_16x16x32_bf16 %0, %1, %2, %0" : "+v"(d) : "v"(a), "v"(b))

// ---- one elementwise pass: build cbmB, CW, WhhB, W1aB, W2B, W3pB, w0 ----
__global__ __launch_bounds__(256) void k_cvtall(
    const float* __restrict__ c, const float* __restrict__ bv,
    const float* __restrict__ mv, const float* __restrict__ W_ih,
    const float* __restrict__ W_hh, const float* __restrict__ W1,
    const float* __restrict__ W2, const float* __restrict__ W3,
    unsigned short* __restrict__ cbmB, unsigned short* __restrict__ CW,
    unsigned short* __restrict__ WhhB, unsigned short* __restrict__ W1aB,
    unsigned short* __restrict__ W2B, unsigned short* __restrict__ W3pB,
    float* __restrict__ w0) {
  int idx = blockIdx.x*256 + threadIdx.x;
  if (idx < 1048576) {            // cbmB [4096][256], K-padded
    int row = idx >> 8, k = idx & 255;
    float v = 0.f;
    if (k < 80)       v = c [row*80 + k];
    else if (k < 144) v = bv[row*64 + (k-80)];
    else if (k < 208) v = mv[row*64 + (k-144)];
    cbmB[idx] = f2bf(v);
    return;
  }
  idx -= 1048576;
  if (idx < 262144) {             // CW [1024][256]: W_ih cols 1.. | W1 cols 256..
    int n = idx >> 8, k = idx & 255;
    float v = 0.f;
    if (n < 768) { if (k < 208) v = W_ih[n*209 + 1 + k]; }
    else         { if (k < 208) v = W1[(n-768)*464 + 256 + k]; }
    CW[idx] = f2bf(v);
    return;
  }
  idx -= 262144;
  if (idx < 196608) { WhhB[idx] = f2bf(W_hh[idx]); return; }
  idx -= 196608;
  if (idx < 65536) { int n = idx>>8, k = idx&255; W1aB[idx] = f2bf(W1[n*464+k]); return; }
  idx -= 65536;
  if (idx < 65536) { W2B[idx] = f2bf(W2[idx]); return; }
  idx -= 65536;
  if (idx < 16384) {
    int n = idx >> 8;
    float v = 0.f;
    if (n < 60) v = W3[idx];
    W3pB[idx] = f2bf(v);
    return;
  }
  idx -= 16384;
  if (idx < 768) w0[idx] = W_ih[idx*209];
}

// ---- pre-GEMM: [4096 x 1024 x 256(pad)] -> gi (+biases) / P1 (+b1) ----
__global__ __launch_bounds__(512) void k_pre(
    const unsigned short* __restrict__ A, const unsigned short* __restrict__ Bw,
    const float* __restrict__ b_ih, const float* __restrict__ b_hh,
    const float* __restrict__ b1,
    float* __restrict__ gi, float* __restrict__ P1) {
  __shared__ __align__(16) unsigned short As[128*64];
  __shared__ __align__(16) unsigned short Bs[128*64];
  int tid = threadIdx.x;
  int rb = blockIdx.x >> 3, cb = blockIdx.x & 7;
  long row0 = (long)rb * 128;
  int n0 = cb * 128;
  int wv = tid >> 6, lane = tid & 63;
  int lq = lane >> 4, l16 = lane & 15;
  int wrg = wv & 3, wcg = wv >> 2;
  const int w64 = tid & ~63;        // wave-uniform slot base
  f32x4 acc[2][4];
#pragma unroll
  for (int i = 0; i < 2; ++i)
#pragma unroll
    for (int j = 0; j < 4; ++j) acc[i][j] = (f32x4){0.f,0.f,0.f,0.f};
  for (int kb = 0; kb < 256; kb += 64) {
#pragma unroll
    for (int i = 0; i < 2; ++i) {
      int s = i*512 + tid;
      int r = s >> 3, cg = (s & 7) ^ (r & 7);
      gload16(&A[(row0 + r)*256 + kb + cg*8],        &As[(i*512 + w64)*8]);
      gload16(&Bw[(long)(n0 + r)*256 + kb + cg*8],   &Bs[(i*512 + w64)*8]);
    }
    __syncthreads();
#pragma unroll
    for (int kc = 0; kc < 2; ++kc) {
      int csel = kc*4 + lq;
      bf16x8 af[2];
#pragma unroll
      for (int rt = 0; rt < 2; ++rt) {
        int r = wrg*32 + rt*16 + l16;
        af[rt] = *(const bf16x8*)&As[r*64 + ((csel ^ (r & 7)))*8];
      }
#pragma unroll
      for (int ct = 0; ct < 4; ++ct) {
        int n = wcg*64 + ct*16 + l16;
        bf16x8 bfr = *(const bf16x8*)&Bs[n*64 + ((csel ^ (n & 7)))*8];
        acc[0][ct] = __builtin_amdgcn_mfma_f32_16x16x32_bf16(af[0], bfr, acc[0][ct], 0, 0, 0);
        acc[1][ct] = __builtin_amdgcn_mfma_f32_16x16x32_bf16(af[1], bfr, acc[1][ct], 0, 0, 0);
      }
    }
    __syncthreads();
  }
#pragma unroll
  for (int rt = 0; rt < 2; ++rt)
#pragma unroll
    for (int q = 0; q < 4; ++q) {
      long row = row0 + wrg*32 + rt*16 + lq*4 + q;
#pragma unroll
      for (int ct = 0; ct < 4; ++ct) {
        int n = n0 + wcg*64 + ct*16 + l16;
        float v = acc[rt][ct][q];
        if (n < 512)      gi[row*G3 + n] = v + b_ih[n] + b_hh[n];
        else if (n < 768) gi[row*G3 + n] = v + b_ih[n];
        else              P1[row*256 + (n-768)] = v + b1[n-768];
      }
    }
}

// ---- persistent GRU, templated for ablation (R25 measurement round).
// MODE 0: full (the real pipeline kernel, nsteps=64).
// MODE 1: copy-out removed (stores+tail sunk)  -> isolates store/drain cost.
// MODE 2: MFMA removed (af sunk, weights kept) -> isolates MFMA chain cost.
// Variants run nsteps=128 on scratch-overwritten state, launched BEFORE the
// real k_gru which fully rewrites hs; outputs bit-identical. ----
template<int MODE>
__global__ __attribute__((amdgpu_flat_work_group_size(256, 256)))
__attribute__((amdgpu_waves_per_eu(1, 1)))
void k_gru_t(
    const float* __restrict__ z, const float* __restrict__ gi,
    const unsigned short* __restrict__ WhhB, const float* __restrict__ b_hh,
    const float* __restrict__ w0, unsigned short* __restrict__ hs, int nsteps) {
  __shared__ __align__(16) unsigned short hbf[2*16*256];  // two 8 KB buffers
  __shared__ __align__(16) float gis[768*20];             // gi^T, stride 20 fp32
  __shared__ __align__(16) float zs[64*16];               // z^T [t][row]
  __shared__ float wls[768 + 256];                        // w0 | b_hh n-gate
  int tid = threadIdx.x;
  int wv = tid >> 6, lane = tid & 63;
  int lq = lane >> 4, l16 = lane & 15;
  int row0 = blockIdx.x * 16;

  // ---- resident weights: wave wv owns gate-cols {g*256 + wv*64 .. +64} ----
  bf16x8 wfA[2][4][8];  // gates r,u: 64 frags = 256 AGPRs (full AGPR file)
  bf16x8 wfN[4][8];     // gate n:    32 frags = 128 VGPRs
#pragma unroll
  for (int g = 0; g < 2; ++g)
#pragma unroll
    for (int cf = 0; cf < 4; ++cf)
#pragma unroll
      for (int ks = 0; ks < 8; ++ks) {
        wfA[g][cf][ks] = *(const bf16x8*)&WhhB[
            (long)(g*256 + wv*64 + cf*16 + l16)*256 + ks*32 + lq*8];
        asm volatile("" : "+a"(wfA[g][cf][ks]));
      }
#pragma unroll
  for (int cf = 0; cf < 4; ++cf)
#pragma unroll
    for (int ks = 0; ks < 8; ++ks) {
      wfN[cf][ks] = *(const bf16x8*)&WhhB[
          (long)(512 + wv*64 + cf*16 + l16)*256 + ks*32 + lq*8];
      asm volatile("" : "+v"(wfN[cf][ks]));
    }

  for (int i = tid; i < 768; i += 256) wls[i] = w0[i];
  for (int i = tid; i < 256; i += 256) wls[768 + i] = b_hh[512 + i];
  for (int i = tid; i < 1024; i += 256) {
    int t = i >> 4, r = i & 15;
    zs[i] = z[(row0+r)*64 + t];
  }
#pragma unroll
  for (int i = 0; i < 12; ++i) {           // gi -> gis (transposed, stride 20)
    int s = i*256 + tid;                    // float4 index, 0..3071
    int r = s / 192, c4 = (s - r*192)*4;
    float4 v = *(const float4*)&gi[(long)(row0+r)*768 + c4];
    gis[(c4+0)*20 + r] = v.x;
    gis[(c4+1)*20 + r] = v.y;
    gis[(c4+2)*20 + r] = v.z;
    gis[(c4+3)*20 + r] = v.w;
  }
  for (int i = tid; i < 2048; i += 256) ((unsigned int*)hbf)[i] = 0u;

  float hp[4][4];
#pragma unroll
  for (int i = 0; i < 4; ++i)
#pragma unroll
    for (int j = 0; j < 4; ++j) hp[i][j] = 0.f;

  const int s7 = l16 & 7;
  const int arow = l16*256;
  const int r4 = lq*4;
  // copy-out roles: 256 threads move 16 rows x 512 B per step
  const int cr = tid >> 4;          // row 0..15
  const int chA = tid & 15;         // chunk 0..15
  const int chB = chA + 16;         // chunk 16..31
  const int cswz = cr & 7;
  unsigned short* cbase = hs + (long)(row0+cr)*64*256 + chA*8;
  __syncthreads();

#pragma unroll 1
  for (int t = 0; t < nsteps; ++t) {
    const int co = (t & 1) << 12;
    const int no = co ^ 4096;
    float zp[4];
    {
      float4 zv4 = *(const float4*)&zs[(t ? ((t-1) & 63) : 0)*16 + r4];
#pragma unroll
      for (int q = 0; q < 4; ++q) zp[q] = t ? (&zv4.x)[q] : -1.0f;
    }
    // stream h_{t-1} to global (reads co, overlaps with MFMA below)
    if (t) {
      uint4 c0 = *(const uint4*)&hbf[co + cr*256 + ((chA ^ cswz))*8];
      uint4 c1 = *(const uint4*)&hbf[co + cr*256 + ((chB ^ cswz))*8];
      if constexpr (MODE == 1) {
        asm volatile("" :: "v"(*(const f32x4*)&c0), "v"(*(const f32x4*)&c1));
      } else {
        *(uint4*)(cbase + ((t-1) & 63)*256)       = c0;
        *(uint4*)(cbase + ((t-1) & 63)*256 + 128) = c1;
      }
    }
#pragma unroll
    for (int hf = 0; hf < 2; ++hf) {        // two column-halves (cf 0-1, 2-3)
      f32x4 acc[3][2];
#pragma unroll
      for (int c2 = 0; c2 < 2; ++c2) {
        int cf = hf*2 + c2;
        int hc = wv*64 + cf*16 + l16;
        f32x4 gR = *(const f32x4*)&gis[hc*20 + r4];
        f32x4 gU = *(const f32x4*)&gis[(256+hc)*20 + r4];
        float w0r = wls[hc], w0u = wls[256+hc], bn = wls[768+hc];
#pragma unroll
        for (int q = 0; q < 4; ++q) {
          acc[0][c2][q] = gR[q] + zp[q]*w0r;
          acc[1][c2][q] = gU[q] + zp[q]*w0u;
          acc[2][c2][q] = bn;
        }
      }
      // VALU write -> MFMA srcC hazard (2 wait states), dataflow-pinned
      asm volatile("s_nop 1"
        : "+v"(acc[0][0]), "+v"(acc[0][1]), "+v"(acc[1][0]),
          "+v"(acc[1][1]), "+v"(acc[2][0]), "+v"(acc[2][1]));
#pragma unroll
      for (int ks = 0; ks < 8; ++ks) {
        bf16x8 af = *(const bf16x8*)&hbf[co + arow + ((ks*4+lq) ^ s7)*8];
        if constexpr (MODE == 2) {
          asm volatile("" :: "v"(af));
        } else {
#pragma unroll
          for (int c2 = 0; c2 < 2; ++c2) {
            int cf = hf*2 + c2;
            MFMA_BA(acc[0][c2], af, wfA[0][cf][ks]);
            MFMA_BA(acc[1][c2], af, wfA[1][cf][ks]);
            MFMA_BV(acc[2][c2], af, wfN[cf][ks]);
          }
        }
      }
      // MFMA write -> VALU read hazard (<=11 wait states for 4-pass)
      asm volatile("s_nop 7\n\ts_nop 7"
        : "+v"(acc[0][0]), "+v"(acc[0][1]), "+v"(acc[1][0]),
          "+v"(acc[1][1]), "+v"(acc[2][0]), "+v"(acc[2][1]));
#pragma unroll
      for (int c2 = 0; c2 < 2; ++c2) {
        int cf = hf*2 + c2;
        int hc = wv*64 + cf*16 + l16;
        int hchunk = hc >> 3, hlow = hc & 7;
        float w0n = wls[512 + hc];
        f32x4 gN = *(const f32x4*)&gis[(512+hc)*20 + r4];
#pragma unroll
        for (int q = 0; q < 4; ++q) {
          int r = r4 + q;
          float rr = sigm(acc[0][c2][q]);
          float uu = sigm(acc[1][c2][q]);
          float nn = tanh_fast(gN[q] + zp[q]*w0n + rr*acc[2][c2][q]);
          float hn = uu*(hp[cf][q] - nn) + nn;
          hp[cf][q] = hn;
          hbf[no + r*256 + ((hchunk ^ (r & 7)))*8 + hlow] = f2bf(hn);
        }
      }
    }
    __syncthreads();
  }
  {
    uint4 c0 = *(const uint4*)&hbf[0 + cr*256 + ((chA ^ cswz))*8];
    uint4 c1 = *(const uint4*)&hbf[0 + cr*256 + ((chB ^ cswz))*8];
    if constexpr (MODE == 1) {
      asm volatile("" :: "v"(*(const f32x4*)&c0), "v"(*(const f32x4*)&c1));
    } else {
      *(uint4*)(cbase + 63*256)       = c0;
      *(uint4*)(cbase + 63*256 + 128) = c1;
    }
  }
}

// ---- fused MLP layer1+2+3 + mixture likelihood (R21, gload_lds staging) ----
__global__ __launch_bounds__(512) void k_mlp(
    const unsigned short* __restrict__ A, const unsigned short* __restrict__ W1aB,
    const float* __restrict__ P1, const unsigned short* __restrict__ W2B,
    const float* __restrict__ b2, const unsigned short* __restrict__ W3pB,
    const float* __restrict__ b3, const float* __restrict__ z,
    float* __restrict__ ll) {
  __shared__ __align__(16) unsigned short As[128*64];
  __shared__ __align__(16) unsigned short Bs[256*64];
  __shared__ __align__(16) unsigned short H[128*256];
  int tid = threadIdx.x;
  long row0 = (long)blockIdx.x * 128;
  int wv = tid >> 6, lane = tid & 63;
  int lq = lane >> 4, l16 = lane & 15;
  int wrg = wv & 3, wcg = wv >> 2;
  const int w64 = tid & ~63;        // wave-uniform slot base
  f32x4 acc[2][8];

  // ======== GEMM1: h1 = tanh(hs @ W1a^T + P1) -> H (swizzled) ========
#pragma unroll
  for (int i = 0; i < 2; ++i)
#pragma unroll
    for (int j = 0; j < 8; ++j) acc[i][j] = (f32x4){0.f,0.f,0.f,0.f};
  for (int kb = 0; kb < 256; kb += 64) {
#pragma unroll
    for (int i = 0; i < 2; ++i) {
      int s = i*512 + tid;
      int r = s >> 3, cg = (s & 7) ^ (r & 7);
      gload16(&A[(row0 + r)*256 + kb + cg*8], &As[(i*512 + w64)*8]);
    }
#pragma unroll
    for (int i = 0; i < 4; ++i) {
      int s = i*512 + tid;
      int r = s >> 3, cg = (s & 7) ^ (r & 7);
      gload16(&W1aB[(long)r*256 + kb + cg*8], &Bs[(i*512 + w64)*8]);
    }
    __syncthreads();
#pragma unroll
    for (int kc = 0; kc < 2; ++kc) {
      int csel = kc*4 + lq;
      bf16x8 af[2];
#pragma unroll
      for (int rt = 0; rt < 2; ++rt) {
        int r = wrg*32 + rt*16 + l16;
        af[rt] = *(const bf16x8*)&As[r*64 + ((csel ^ (r & 7)))*8];
      }
#pragma unroll
      for (int ct = 0; ct < 8; ++ct) {
        int n = wcg*128 + ct*16 + l16;
        bf16x8 bfr = *(const bf16x8*)&Bs[n*64 + ((csel ^ (n & 7)))*8];
        acc[0][ct] = __builtin_amdgcn_mfma_f32_16x16x32_bf16(af[0], bfr, acc[0][ct], 0, 0, 0);
        acc[1][ct] = __builtin_amdgcn_mfma_f32_16x16x32_bf16(af[1], bfr, acc[1][ct], 0, 0, 0);
      }
    }
    __syncthreads();
  }
  // h1 -> H (bf16, swizzled for A-side reads in GEMM2)
#pragma unroll
  for (int rt = 0; rt < 2; ++rt)
#pragma unroll
    for (int q = 0; q < 4; ++q) {
      int lr = wrg*32 + rt*16 + lq*4 + q;
      long row = row0 + lr;
#pragma unroll
      for (int ct = 0; ct < 8; ++ct) {
        int n = wcg*128 + ct*16 + l16;
        float b = P1[(row >> 6)*256 + n];
        H[lr*256 + (((n >> 3) ^ swz(lr))*8 + (n & 7))] =
            f2bf(tanh_fast(acc[rt][ct][q] + b));
      }
    }
  __syncthreads();

  // ======== GEMM2: h2 = tanh(h1 @ W2^T + b2), A-side from H ========
#pragma unroll
  for (int i = 0; i < 2; ++i)
#pragma unroll
    for (int j = 0; j < 8; ++j) acc[i][j] = (f32x4){0.f,0.f,0.f,0.f};
  for (int kb = 0; kb < 256; kb += 64) {
#pragma unroll
    for (int i = 0; i < 4; ++i) {
      int s = i*512 + tid;
      int r = s >> 3, cg = (s & 7) ^ (r & 7);
      gload16(&W2B[(long)r*256 + kb + cg*8], &Bs[(i*512 + w64)*8]);
    }
    __syncthreads();
#pragma unroll
    for (int kc = 0; kc < 2; ++kc) {
      int csel = kc*4 + lq;
      int chunk = (kb >> 3) + csel;
      bf16x8 af[2];
#pragma unroll
      for (int rt = 0; rt < 2; ++rt) {
        int r = wrg*32 + rt*16 + l16;
        af[rt] = *(const bf16x8*)&H[r*256 + ((chunk ^ swz(r)))*8];
      }
#pragma unroll
      for (int ct = 0; ct < 8; ++ct) {
        int n = wcg*128 + ct*16 + l16;
        bf16x8 bfr = *(const bf16x8*)&Bs[n*64 + ((csel ^ (n & 7)))*8];
        acc[0][ct] = __builtin_amdgcn_mfma_f32_16x16x32_bf16(af[0], bfr, acc[0][ct], 0, 0, 0);
        acc[1][ct] = __builtin_amdgcn_mfma_f32_16x16x32_bf16(af[1], bfr, acc[1][ct], 0, 0, 0);
      }
    }
    __syncthreads();   // final iteration: drains all H reads -> safe to overwrite
  }
  // h2 -> H (overwrite h1; same swizzle)
#pragma unroll
  for (int rt = 0; rt < 2; ++rt)
#pragma unroll
    for (int q = 0; q < 4; ++q) {
      int lr = wrg*32 + rt*16 + lq*4 + q;
#pragma unroll
      for (int ct = 0; ct < 8; ++ct) {
        int n = wcg*128 + ct*16 + l16;
        H[lr*256 + (((n >> 3) ^ swz(lr))*8 + (n & 7))] =
            f2bf(tanh_fast(acc[rt][ct][q] + b2[n]));
      }
    }
  __syncthreads();   // separate H-write phase from Bs staging
  // stage W3p into Bs (64 x 256), swizzled (LDS-dest swizzle: keep sync path)
#pragma unroll
  for (int i = 0; i < 4; ++i) {
    int s = i*512 + tid;
    int r = s >> 5, cc = s & 31;
    *(uint4*)&Bs[r*256 + ((cc ^ swz(r)))*8] = *(const uint4*)&W3pB[r*256 + cc*8];
  }
  __syncthreads();

  // ======== GEMM3 + likelihood: each wave owns 16 rows x 64 params ========
  f32x4 pacc[4];
#pragma unroll
  for (int j = 0; j < 4; ++j) pacc[j] = (f32x4){0.f,0.f,0.f,0.f};
#pragma unroll
  for (int ks = 0; ks < 8; ++ks) {
    int chunk = ks*4 + lq;
    int ar = wv*16 + l16;
    bf16x8 af = *(const bf16x8*)&H[ar*256 + ((chunk ^ swz(ar)))*8];
#pragma unroll
    for (int ct = 0; ct < 4; ++ct) {
      int br = ct*16 + l16;
      bf16x8 bfr = *(const bf16x8*)&Bs[br*256 + ((chunk ^ swz(br)))*8];
      pacc[ct] = __builtin_amdgcn_mfma_f32_16x16x32_bf16(af, bfr, pacc[ct], 0, 0, 0);
    }
  }
  // params to own LDS region (reuse H rows of this wave), stride 68 fp32
  float* Ps = (float*)&H[wv*16*256];
#pragma unroll
  for (int ct = 0; ct < 4; ++ct) {
    int n = ct*16 + l16;
    float b = (n < 60) ? b3[n] : 0.0f;
#pragma unroll
    for (int q = 0; q < 4; ++q)
      Ps[(lq*4 + q)*68 + n] = pacc[ct][q] + b;
  }
  // per-row likelihood (wave-internal)
  if (lane < 16) {
    long grow = row0 + wv*16 + lane;
    float zv = z[grow];
    const float* p = &Ps[lane*68];
    float mx1 = -1e30f;
#pragma unroll
    for (int i = 0; i < NK; ++i) mx1 = fmaxf(mx1, p[i]);
    float s1 = 0.0f;
#pragma unroll
    for (int i = 0; i < NK; ++i) s1 += __expf(p[i] - mx1);
    float lse1 = mx1 + __logf(s1);
    float a[NK];
    float mx2 = -1e30f;
#pragma unroll
    for (int i = 0; i < NK; ++i) {
      float lg = p[i], me = p[20+i], ls = p[40+i];
      float e = __expf(-ls);
      float d = (zv - me) * e;
      float ai = -0.5f*d*d - ls - 0.5f*LOG2PI + lg;
      a[i] = ai;
      mx2 = fmaxf(mx2, ai);
    }
    float s2 = 0.0f;
#pragma unroll
    for (int i = 0; i < NK; ++i) s2 += __expf(a[i] - mx2);
    float lse2 = mx2 + __logf(s2);
    ll[grow] = lse2 - lse1;
  }
}

// out[b] = sum_{t < S_b} ll[b,t]
__global__ __launch_bounds__(256) void k_final(const float* __restrict__ bv,
    const float* __restrict__ mv, const float* __restrict__ ll,
    float* __restrict__ out) {
  int tid = threadIdx.x;
  int wave = tid >> 6, lane = tid & 63;
  int b = blockIdx.x*4 + wave;
  float q = mv[b*64 + lane] * (1.0f - bv[b*64 + lane]);
  unsigned long long bal = __ballot(q > 0.5f);
  int S = __popcll(bal);
  float val = (lane < S) ? ll[(long)b*64 + lane] : 0.0f;
#pragma unroll
  for (int off = 32; off > 0; off >>= 1) val += __shfl_down(val, off);
  if (lane == 0) out[b] = val;
}

extern "C" void kernel_launch(void* const* d_in, const int* in_sizes, int n_in,
                              void* d_out, int out_size, void* d_ws, size_t ws_size,
                              hipStream_t stream) {
  const float* z    = (const float*)d_in[0];
  const float* c    = (const float*)d_in[1];
  const float* bv   = (const float*)d_in[2];
  const float* mv   = (const float*)d_in[3];
  const float* W_ih = (const float*)d_in[4];
  const float* W_hh = (const float*)d_in[5];
  const float* b_ih = (const float*)d_in[6];
  const float* b_hh = (const float*)d_in[7];
  const float* W1   = (const float*)d_in[8];
  const float* b1   = (const float*)d_in[9];
  const float* W2   = (const float*)d_in[10];
  const float* b2   = (const float*)d_in[11];
  const float* W3   = (const float*)d_in[12];
  const float* b3   = (const float*)d_in[13];
  float* out = (float*)d_out;

  char* p = (char*)d_ws;
  auto alloc = [&](size_t bytes) {
    char* q = p;
    p += (bytes + 255) & ~(size_t)255;
    return q;
  };
  unsigned short* cbmB = (unsigned short*)alloc((size_t)BATCH*256*2);
  unsigned short* CW   = (unsigned short*)alloc((size_t)1024*256*2);
  unsigned short* WhhB = (unsigned short*)alloc((size_t)G3*256*2);
  unsigned short* W1aB = (unsigned short*)alloc((size_t)256*256*2);
  unsigned short* W2B  = (unsigned short*)alloc((size_t)256*256*2);
  unsigned short* W3pB = (unsigned short*)alloc((size_t)64*256*2);
  float* w0 = (float*)alloc((size_t)G3*4);
  float* gi = (float*)alloc((size_t)BATCH*G3*4);
  float* P1 = (float*)alloc((size_t)BATCH*256*4);
  float* ll = (float*)alloc((size_t)NROW*4);
  unsigned short* hs = (unsigned short*)alloc((size_t)NROW*HDIM*2);

  k_cvtall<<<6468, 256, 0, stream>>>(c, bv, mv, W_ih, W_hh, W1, W2, W3,
                                     cbmB, CW, WhhB, W1aB, W2B, W3pB, w0);
  k_pre<<<256, 512, 0, stream>>>(cbmB, CW, b_ih, b_hh, b1, gi, P1);
  // --- ablation probes (R25): write only scratch/overwritten state ---
  k_gru_t<1><<<256, 256, 0, stream>>>(z, gi, WhhB, b_hh, w0, hs, 128);
  k_gru_t<2><<<256, 256, 0, stream>>>(z, gi, WhhB, b_hh, w0, hs, 128);
  // --- real pipeline (fully overwrites hs) ---
  k_gru_t<0><<<256, 256, 0, stream>>>(z, gi, WhhB, b_hh, w0, hs, 64);
  k_mlp<<<NROW/128, 512, 0, stream>>>(hs, W1aB, P1, W2B, b2, W3pB, b3, z, ll);
  k_final<<<BATCH/4, 256, 0, stream>>>(bv, mv, ll, out);
}

// Round 12
// 493.479 us; speedup vs baseline: 2.5454x; 2.5454x over previous
//
#include <hip/hip_runtime.h>
#include <hip/hip_bf16.h>

#define BATCH  4096
#define NCC    64
#define HDIM   256
#define G3     768
#define NROW   (BATCH*NCC)   // 262144
#define NK     20
#define LOG2PI 1.8378770664093453f

typedef __attribute__((ext_vector_type(8))) short bf16x8;
typedef __attribute__((ext_vector_type(4))) float f32x4;

__device__ __forceinline__ float sigm(float x) { return 1.0f/(1.0f + __expf(-x)); }
__device__ __forceinline__ float tanh_fast(float x) { return 1.0f - 2.0f/(__expf(2.0f*x) + 1.0f); }
__device__ __forceinline__ unsigned short f2bf(float x) {
  __hip_bfloat16 h = __float2bfloat16(x);
  return __builtin_bit_cast(unsigned short, h);
}
__device__ __forceinline__ int swz(int r) { return (r & 7) ^ ((r & 8) >> 2); }

// Async global->LDS, 16B per lane. LDS dest is WAVE-UNIFORM base + lane*16.
typedef const __attribute__((address_space(1))) unsigned int glb_u32;
typedef __attribute__((address_space(3))) unsigned int lds_u32;
__device__ __forceinline__ void gload16(const unsigned short* g, unsigned short* l) {
  __builtin_amdgcn_global_load_lds((glb_u32*)g, (lds_u32*)l, 16, 0, 0);
}

// MFMA via inline asm: B operand constrained to AGPR ("a") or VGPR ("v").
#define MFMA_BA(d, a, b) \
  asm("v_mfma_f32_16x16x32_bf16 %0, %1, %2, %0" : "+v"(d) : "v"(a), "a"(b))
#define MFMA_BV(d, a, b) \
  asm("v_mfma_f32_16x16x32_bf16 %0, %1, %2, %0" : "+v"(d) : "v"(a), "v"(b))

// ---- one elementwise pass: build cbmB, CW, WhhB, W1aB, W2B, W3pB, w0 ----
__global__ __launch_bounds__(256) void k_cvtall(
    const float* __restrict__ c, const float* __restrict__ bv,
    const float* __restrict__ mv, const float* __restrict__ W_ih,
    const float* __restrict__ W_hh, const float* __restrict__ W1,
    const float* __restrict__ W2, const float* __restrict__ W3,
    unsigned short* __restrict__ cbmB, unsigned short* __restrict__ CW,
    unsigned short* __restrict__ WhhB, unsigned short* __restrict__ W1aB,
    unsigned short* __restrict__ W2B, unsigned short* __restrict__ W3pB,
    float* __restrict__ w0) {
  int idx = blockIdx.x*256 + threadIdx.x;
  if (idx < 1048576) {            // cbmB [4096][256], K-padded
    int row = idx >> 8, k = idx & 255;
    float v = 0.f;
    if (k < 80)       v = c [row*80 + k];
    else if (k < 144) v = bv[row*64 + (k-80)];
    else if (k < 208) v = mv[row*64 + (k-144)];
    cbmB[idx] = f2bf(v);
    return;
  }
  idx -= 1048576;
  if (idx < 262144) {             // CW [1024][256]: W_ih cols 1.. | W1 cols 256..
    int n = idx >> 8, k = idx & 255;
    float v = 0.f;
    if (n < 768) { if (k < 208) v = W_ih[n*209 + 1 + k]; }
    else         { if (k < 208) v = W1[(n-768)*464 + 256 + k]; }
    CW[idx] = f2bf(v);
    return;
  }
  idx -= 262144;
  if (idx < 196608) { WhhB[idx] = f2bf(W_hh[idx]); return; }
  idx -= 196608;
  if (idx < 65536) { int n = idx>>8, k = idx&255; W1aB[idx] = f2bf(W1[n*464+k]); return; }
  idx -= 65536;
  if (idx < 65536) { W2B[idx] = f2bf(W2[idx]); return; }
  idx -= 65536;
  if (idx < 16384) {
    int n = idx >> 8;
    float v = 0.f;
    if (n < 60) v = W3[idx];
    W3pB[idx] = f2bf(v);
    return;
  }
  idx -= 16384;
  if (idx < 768) w0[idx] = W_ih[idx*209];
}

// ---- pre-GEMM: [4096 x 1024 x 256(pad)] -> gi (+biases) / P1 (+b1) ----
__global__ __launch_bounds__(512) void k_pre(
    const unsigned short* __restrict__ A, const unsigned short* __restrict__ Bw,
    const float* __restrict__ b_ih, const float* __restrict__ b_hh,
    const float* __restrict__ b1,
    float* __restrict__ gi, float* __restrict__ P1) {
  __shared__ __align__(16) unsigned short As[128*64];
  __shared__ __align__(16) unsigned short Bs[128*64];
  int tid = threadIdx.x;
  int rb = blockIdx.x >> 3, cb = blockIdx.x & 7;
  long row0 = (long)rb * 128;
  int n0 = cb * 128;
  int wv = tid >> 6, lane = tid & 63;
  int lq = lane >> 4, l16 = lane & 15;
  int wrg = wv & 3, wcg = wv >> 2;
  const int w64 = tid & ~63;        // wave-uniform slot base
  f32x4 acc[2][4];
#pragma unroll
  for (int i = 0; i < 2; ++i)
#pragma unroll
    for (int j = 0; j < 4; ++j) acc[i][j] = (f32x4){0.f,0.f,0.f,0.f};
  for (int kb = 0; kb < 256; kb += 64) {
#pragma unroll
    for (int i = 0; i < 2; ++i) {
      int s = i*512 + tid;
      int r = s >> 3, cg = (s & 7) ^ (r & 7);
      gload16(&A[(row0 + r)*256 + kb + cg*8],        &As[(i*512 + w64)*8]);
      gload16(&Bw[(long)(n0 + r)*256 + kb + cg*8],   &Bs[(i*512 + w64)*8]);
    }
    __syncthreads();
#pragma unroll
    for (int kc = 0; kc < 2; ++kc) {
      int csel = kc*4 + lq;
      bf16x8 af[2];
#pragma unroll
      for (int rt = 0; rt < 2; ++rt) {
        int r = wrg*32 + rt*16 + l16;
        af[rt] = *(const bf16x8*)&As[r*64 + ((csel ^ (r & 7)))*8];
      }
#pragma unroll
      for (int ct = 0; ct < 4; ++ct) {
        int n = wcg*64 + ct*16 + l16;
        bf16x8 bfr = *(const bf16x8*)&Bs[n*64 + ((csel ^ (n & 7)))*8];
        acc[0][ct] = __builtin_amdgcn_mfma_f32_16x16x32_bf16(af[0], bfr, acc[0][ct], 0, 0, 0);
        acc[1][ct] = __builtin_amdgcn_mfma_f32_16x16x32_bf16(af[1], bfr, acc[1][ct], 0, 0, 0);
      }
    }
    __syncthreads();
  }
#pragma unroll
  for (int rt = 0; rt < 2; ++rt)
#pragma unroll
    for (int q = 0; q < 4; ++q) {
      long row = row0 + wrg*32 + rt*16 + lq*4 + q;
#pragma unroll
      for (int ct = 0; ct < 4; ++ct) {
        int n = n0 + wcg*64 + ct*16 + l16;
        float v = acc[rt][ct][q];
        if (n < 512)      gi[row*G3 + n] = v + b_ih[n] + b_hh[n];
        else if (n < 768) gi[row*G3 + n] = v + b_ih[n];
        else              P1[row*256 + (n-768)] = v + b1[n-768];
      }
    }
}

// ---- persistent GRU, R26: hf-halves MERGED.
// R25 ablation: MFMA block = 1.44 us/step (38%), mostly 16x af ds_read
// serialization (read->wait->6 MFMA); copy-out = 0.25; skeleton = 2.37.
// The two hf halves read IDENTICAL af data (af depends on (co,row,ks) only)
// — the hf split (R15, acc-liveness cap) doubled af reads for nothing.
// Merged: acc[3][4] (48 VGPR), single ks loop, 12 MFMA per af read ->
// 8 reads/step instead of 16, 60cyc of issue to hide each read under.
// Accumulation order per acc chain unchanged -> numerics identical. ----
__global__ __attribute__((amdgpu_flat_work_group_size(256, 256)))
__attribute__((amdgpu_waves_per_eu(1, 1)))
void k_gru(
    const float* __restrict__ z, const float* __restrict__ gi,
    const unsigned short* __restrict__ WhhB, const float* __restrict__ b_hh,
    const float* __restrict__ w0, unsigned short* __restrict__ hs) {
  __shared__ __align__(16) unsigned short hbf[2*16*256];  // two 8 KB buffers
  __shared__ __align__(16) float gis[768*20];             // gi^T, stride 20 fp32
  __shared__ __align__(16) float zs[64*16];               // z^T [t][row]
  __shared__ float wls[768 + 256];                        // w0 | b_hh n-gate
  int tid = threadIdx.x;
  int wv = tid >> 6, lane = tid & 63;
  int lq = lane >> 4, l16 = lane & 15;
  int row0 = blockIdx.x * 16;

  // ---- resident weights: wave wv owns gate-cols {g*256 + wv*64 .. +64} ----
  bf16x8 wfA[2][4][8];  // gates r,u: 64 frags = 256 AGPRs (full AGPR file)
  bf16x8 wfN[4][8];     // gate n:    32 frags = 128 VGPRs
#pragma unroll
  for (int g = 0; g < 2; ++g)
#pragma unroll
    for (int cf = 0; cf < 4; ++cf)
#pragma unroll
      for (int ks = 0; ks < 8; ++ks) {
        wfA[g][cf][ks] = *(const bf16x8*)&WhhB[
            (long)(g*256 + wv*64 + cf*16 + l16)*256 + ks*32 + lq*8];
        asm volatile("" : "+a"(wfA[g][cf][ks]));
      }
#pragma unroll
  for (int cf = 0; cf < 4; ++cf)
#pragma unroll
    for (int ks = 0; ks < 8; ++ks) {
      wfN[cf][ks] = *(const bf16x8*)&WhhB[
          (long)(512 + wv*64 + cf*16 + l16)*256 + ks*32 + lq*8];
      asm volatile("" : "+v"(wfN[cf][ks]));
    }

  for (int i = tid; i < 768; i += 256) wls[i] = w0[i];
  for (int i = tid; i < 256; i += 256) wls[768 + i] = b_hh[512 + i];
  for (int i = tid; i < 1024; i += 256) {
    int t = i >> 4, r = i & 15;
    zs[i] = z[(row0+r)*64 + t];
  }
#pragma unroll
  for (int i = 0; i < 12; ++i) {           // gi -> gis (transposed, stride 20)
    int s = i*256 + tid;                    // float4 index, 0..3071
    int r = s / 192, c4 = (s - r*192)*4;
    float4 v = *(const float4*)&gi[(long)(row0+r)*768 + c4];
    gis[(c4+0)*20 + r] = v.x;
    gis[(c4+1)*20 + r] = v.y;
    gis[(c4+2)*20 + r] = v.z;
    gis[(c4+3)*20 + r] = v.w;
  }
  for (int i = tid; i < 2048; i += 256) ((unsigned int*)hbf)[i] = 0u;

  float hp[4][4];
#pragma unroll
  for (int i = 0; i < 4; ++i)
#pragma unroll
    for (int j = 0; j < 4; ++j) hp[i][j] = 0.f;

  const int s7 = l16 & 7;
  const int arow = l16*256;
  const int r4 = lq*4;
  // copy-out roles: 256 threads move 16 rows x 512 B per step
  const int cr = tid >> 4;          // row 0..15
  const int chA = tid & 15;         // chunk 0..15
  const int chB = chA + 16;         // chunk 16..31
  const int cswz = cr & 7;
  unsigned short* cbase = hs + (long)(row0+cr)*64*256 + chA*8;
  __syncthreads();

#pragma unroll 1
  for (int t = 0; t < 64; ++t) {
    const int co = (t & 1) << 12;
    const int no = co ^ 4096;
    float zp[4];
    {
      float4 zv4 = *(const float4*)&zs[(t ? (t-1) : 0)*16 + r4];
#pragma unroll
      for (int q = 0; q < 4; ++q) zp[q] = t ? (&zv4.x)[q] : -1.0f;
    }
    // stream h_{t-1} to global (reads co, overlaps with MFMA below)
    if (t) {
      uint4 c0 = *(const uint4*)&hbf[co + cr*256 + ((chA ^ cswz))*8];
      uint4 c1 = *(const uint4*)&hbf[co + cr*256 + ((chB ^ cswz))*8];
      *(uint4*)(cbase + (t-1)*256)       = c0;
      *(uint4*)(cbase + (t-1)*256 + 128) = c1;
    }
    // ---- acc init: all 4 column-fragments, 3 gates (48 VGPRs) ----
    f32x4 acc[3][4];
#pragma unroll
    for (int cf = 0; cf < 4; ++cf) {
      int hc = wv*64 + cf*16 + l16;
      f32x4 gR = *(const f32x4*)&gis[hc*20 + r4];
      f32x4 gU = *(const f32x4*)&gis[(256+hc)*20 + r4];
      float w0r = wls[hc], w0u = wls[256+hc], bn = wls[768+hc];
#pragma unroll
      for (int q = 0; q < 4; ++q) {
        acc[0][cf][q] = gR[q] + zp[q]*w0r;
        acc[1][cf][q] = gU[q] + zp[q]*w0u;
        acc[2][cf][q] = bn;
      }
    }
    // VALU write -> MFMA srcC hazard (2 wait states), dataflow-pinned
    asm volatile("s_nop 1"
      : "+v"(acc[0][0]), "+v"(acc[0][1]), "+v"(acc[0][2]), "+v"(acc[0][3]),
        "+v"(acc[1][0]), "+v"(acc[1][1]), "+v"(acc[1][2]), "+v"(acc[1][3]),
        "+v"(acc[2][0]), "+v"(acc[2][1]), "+v"(acc[2][2]), "+v"(acc[2][3]));
    // ---- single ks loop: 1 af read feeds 12 MFMAs ----
#pragma unroll
    for (int ks = 0; ks < 8; ++ks) {
      bf16x8 af = *(const bf16x8*)&hbf[co + arow + ((ks*4+lq) ^ s7)*8];
#pragma unroll
      for (int cf = 0; cf < 4; ++cf) {
        MFMA_BA(acc[0][cf], af, wfA[0][cf][ks]);
        MFMA_BA(acc[1][cf], af, wfA[1][cf][ks]);
        MFMA_BV(acc[2][cf], af, wfN[cf][ks]);
      }
    }
    // MFMA write -> VALU read hazard (<=11 wait states for 4-pass)
    asm volatile("s_nop 7\n\ts_nop 7"
      : "+v"(acc[0][0]), "+v"(acc[0][1]), "+v"(acc[0][2]), "+v"(acc[0][3]),
        "+v"(acc[1][0]), "+v"(acc[1][1]), "+v"(acc[1][2]), "+v"(acc[1][3]),
        "+v"(acc[2][0]), "+v"(acc[2][1]), "+v"(acc[2][2]), "+v"(acc[2][3]));
    // ---- gate epilogue, all 4 column-fragments ----
#pragma unroll
    for (int cf = 0; cf < 4; ++cf) {
      int hc = wv*64 + cf*16 + l16;
      int hchunk = hc >> 3, hlow = hc & 7;
      float w0n = wls[512 + hc];
      f32x4 gN = *(const f32x4*)&gis[(512+hc)*20 + r4];
#pragma unroll
      for (int q = 0; q < 4; ++q) {
        int r = r4 + q;
        float rr = sigm(acc[0][cf][q]);
        float uu = sigm(acc[1][cf][q]);
        float nn = tanh_fast(gN[q] + zp[q]*w0n + rr*acc[2][cf][q]);
        float hn = uu*(hp[cf][q] - nn) + nn;
        hp[cf][q] = hn;
        hbf[no + r*256 + ((hchunk ^ (r & 7)))*8 + hlow] = f2bf(hn);
      }
    }
    __syncthreads();
  }
  {
    uint4 c0 = *(const uint4*)&hbf[0 + cr*256 + ((chA ^ cswz))*8];
    uint4 c1 = *(const uint4*)&hbf[0 + cr*256 + ((chB ^ cswz))*8];
    *(uint4*)(cbase + 63*256)       = c0;
    *(uint4*)(cbase + 63*256 + 128) = c1;
  }
}

// ---- fused MLP layer1+2+3 + mixture likelihood (R21, gload_lds staging) ----
__global__ __launch_bounds__(512) void k_mlp(
    const unsigned short* __restrict__ A, const unsigned short* __restrict__ W1aB,
    const float* __restrict__ P1, const unsigned short* __restrict__ W2B,
    const float* __restrict__ b2, const unsigned short* __restrict__ W3pB,
    const float* __restrict__ b3, const float* __restrict__ z,
    float* __restrict__ ll) {
  __shared__ __align__(16) unsigned short As[128*64];
  __shared__ __align__(16) unsigned short Bs[256*64];
  __shared__ __align__(16) unsigned short H[128*256];
  int tid = threadIdx.x;
  long row0 = (long)blockIdx.x * 128;
  int wv = tid >> 6, lane = tid & 63;
  int lq = lane >> 4, l16 = lane & 15;
  int wrg = wv & 3, wcg = wv >> 2;
  const int w64 = tid & ~63;        // wave-uniform slot base
  f32x4 acc[2][8];

  // ======== GEMM1: h1 = tanh(hs @ W1a^T + P1) -> H (swizzled) ========
#pragma unroll
  for (int i = 0; i < 2; ++i)
#pragma unroll
    for (int j = 0; j < 8; ++j) acc[i][j] = (f32x4){0.f,0.f,0.f,0.f};
  for (int kb = 0; kb < 256; kb += 64) {
#pragma unroll
    for (int i = 0; i < 2; ++i) {
      int s = i*512 + tid;
      int r = s >> 3, cg = (s & 7) ^ (r & 7);
      gload16(&A[(row0 + r)*256 + kb + cg*8], &As[(i*512 + w64)*8]);
    }
#pragma unroll
    for (int i = 0; i < 4; ++i) {
      int s = i*512 + tid;
      int r = s >> 3, cg = (s & 7) ^ (r & 7);
      gload16(&W1aB[(long)r*256 + kb + cg*8], &Bs[(i*512 + w64)*8]);
    }
    __syncthreads();
#pragma unroll
    for (int kc = 0; kc < 2; ++kc) {
      int csel = kc*4 + lq;
      bf16x8 af[2];
#pragma unroll
      for (int rt = 0; rt < 2; ++rt) {
        int r = wrg*32 + rt*16 + l16;
        af[rt] = *(const bf16x8*)&As[r*64 + ((csel ^ (r & 7)))*8];
      }
#pragma unroll
      for (int ct = 0; ct < 8; ++ct) {
        int n = wcg*128 + ct*16 + l16;
        bf16x8 bfr = *(const bf16x8*)&Bs[n*64 + ((csel ^ (n & 7)))*8];
        acc[0][ct] = __builtin_amdgcn_mfma_f32_16x16x32_bf16(af[0], bfr, acc[0][ct], 0, 0, 0);
        acc[1][ct] = __builtin_amdgcn_mfma_f32_16x16x32_bf16(af[1], bfr, acc[1][ct], 0, 0, 0);
      }
    }
    __syncthreads();
  }
  // h1 -> H (bf16, swizzled for A-side reads in GEMM2)
#pragma unroll
  for (int rt = 0; rt < 2; ++rt)
#pragma unroll
    for (int q = 0; q < 4; ++q) {
      int lr = wrg*32 + rt*16 + lq*4 + q;
      long row = row0 + lr;
#pragma unroll
      for (int ct = 0; ct < 8; ++ct) {
        int n = wcg*128 + ct*16 + l16;
        float b = P1[(row >> 6)*256 + n];
        H[lr*256 + (((n >> 3) ^ swz(lr))*8 + (n & 7))] =
            f2bf(tanh_fast(acc[rt][ct][q] + b));
      }
    }
  __syncthreads();

  // ======== GEMM2: h2 = tanh(h1 @ W2^T + b2), A-side from H ========
#pragma unroll
  for (int i = 0; i < 2; ++i)
#pragma unroll
    for (int j = 0; j < 8; ++j) acc[i][j] = (f32x4){0.f,0.f,0.f,0.f};
  for (int kb = 0; kb < 256; kb += 64) {
#pragma unroll
    for (int i = 0; i < 4; ++i) {
      int s = i*512 + tid;
      int r = s >> 3, cg = (s & 7) ^ (r & 7);
      gload16(&W2B[(long)r*256 + kb + cg*8], &Bs[(i*512 + w64)*8]);
    }
    __syncthreads();
#pragma unroll
    for (int kc = 0; kc < 2; ++kc) {
      int csel = kc*4 + lq;
      int chunk = (kb >> 3) + csel;
      bf16x8 af[2];
#pragma unroll
      for (int rt = 0; rt < 2; ++rt) {
        int r = wrg*32 + rt*16 + l16;
        af[rt] = *(const bf16x8*)&H[r*256 + ((chunk ^ swz(r)))*8];
      }
#pragma unroll
      for (int ct = 0; ct < 8; ++ct) {
        int n = wcg*128 + ct*16 + l16;
        bf16x8 bfr = *(const bf16x8*)&Bs[n*64 + ((csel ^ (n & 7)))*8];
        acc[0][ct] = __builtin_amdgcn_mfma_f32_16x16x32_bf16(af[0], bfr, acc[0][ct], 0, 0, 0);
        acc[1][ct] = __builtin_amdgcn_mfma_f32_16x16x32_bf16(af[1], bfr, acc[1][ct], 0, 0, 0);
      }
    }
    __syncthreads();   // final iteration: drains all H reads -> safe to overwrite
  }
  // h2 -> H (overwrite h1; same swizzle)
#pragma unroll
  for (int rt = 0; rt < 2; ++rt)
#pragma unroll
    for (int q = 0; q < 4; ++q) {
      int lr = wrg*32 + rt*16 + lq*4 + q;
#pragma unroll
      for (int ct = 0; ct < 8; ++ct) {
        int n = wcg*128 + ct*16 + l16;
        H[lr*256 + (((n >> 3) ^ swz(lr))*8 + (n & 7))] =
            f2bf(tanh_fast(acc[rt][ct][q] + b2[n]));
      }
    }
  __syncthreads();   // separate H-write phase from Bs staging
  // stage W3p into Bs (64 x 256), swizzled (LDS-dest swizzle: keep sync path)
#pragma unroll
  for (int i = 0; i < 4; ++i) {
    int s = i*512 + tid;
    int r = s >> 5, cc = s & 31;
    *(uint4*)&Bs[r*256 + ((cc ^ swz(r)))*8] = *(const uint4*)&W3pB[r*256 + cc*8];
  }
  __syncthreads();

  // ======== GEMM3 + likelihood: each wave owns 16 rows x 64 params ========
  f32x4 pacc[4];
#pragma unroll
  for (int j = 0; j < 4; ++j) pacc[j] = (f32x4){0.f,0.f,0.f,0.f};
#pragma unroll
  for (int ks = 0; ks < 8; ++ks) {
    int chunk = ks*4 + lq;
    int ar = wv*16 + l16;
    bf16x8 af = *(const bf16x8*)&H[ar*256 + ((chunk ^ swz(ar)))*8];
#pragma unroll
    for (int ct = 0; ct < 4; ++ct) {
      int br = ct*16 + l16;
      bf16x8 bfr = *(const bf16x8*)&Bs[br*256 + ((chunk ^ swz(br)))*8];
      pacc[ct] = __builtin_amdgcn_mfma_f32_16x16x32_bf16(af, bfr, pacc[ct], 0, 0, 0);
    }
  }
  // params to own LDS region (reuse H rows of this wave), stride 68 fp32
  float* Ps = (float*)&H[wv*16*256];
#pragma unroll
  for (int ct = 0; ct < 4; ++ct) {
    int n = ct*16 + l16;
    float b = (n < 60) ? b3[n] : 0.0f;
#pragma unroll
    for (int q = 0; q < 4; ++q)
      Ps[(lq*4 + q)*68 + n] = pacc[ct][q] + b;
  }
  // per-row likelihood (wave-internal)
  if (lane < 16) {
    long grow = row0 + wv*16 + lane;
    float zv = z[grow];
    const float* p = &Ps[lane*68];
    float mx1 = -1e30f;
#pragma unroll
    for (int i = 0; i < NK; ++i) mx1 = fmaxf(mx1, p[i]);
    float s1 = 0.0f;
#pragma unroll
    for (int i = 0; i < NK; ++i) s1 += __expf(p[i] - mx1);
    float lse1 = mx1 + __logf(s1);
    float a[NK];
    float mx2 = -1e30f;
#pragma unroll
    for (int i = 0; i < NK; ++i) {
      float lg = p[i], me = p[20+i], ls = p[40+i];
      float e = __expf(-ls);
      float d = (zv - me) * e;
      float ai = -0.5f*d*d - ls - 0.5f*LOG2PI + lg;
      a[i] = ai;
      mx2 = fmaxf(mx2, ai);
    }
    float s2 = 0.0f;
#pragma unroll
    for (int i = 0; i < NK; ++i) s2 += __expf(a[i] - mx2);
    float lse2 = mx2 + __logf(s2);
    ll[grow] = lse2 - lse1;
  }
}

// out[b] = sum_{t < S_b} ll[b,t]
__global__ __launch_bounds__(256) void k_final(const float* __restrict__ bv,
    const float* __restrict__ mv, const float* __restrict__ ll,
    float* __restrict__ out) {
  int tid = threadIdx.x;
  int wave = tid >> 6, lane = tid & 63;
  int b = blockIdx.x*4 + wave;
  float q = mv[b*64 + lane] * (1.0f - bv[b*64 + lane]);
  unsigned long long bal = __ballot(q > 0.5f);
  int S = __popcll(bal);
  float val = (lane < S) ? ll[(long)b*64 + lane] : 0.0f;
#pragma unroll
  for (int off = 32; off > 0; off >>= 1) val += __shfl_down(val, off);
  if (lane == 0) out[b] = val;
}

extern "C" void kernel_launch(void* const* d_in, const int* in_sizes, int n_in,
                              void* d_out, int out_size, void* d_ws, size_t ws_size,
                              hipStream_t stream) {
  const float* z    = (const float*)d_in[0];
  const float* c    = (const float*)d_in[1];
  const float* bv   = (const float*)d_in[2];
  const float* mv   = (const float*)d_in[3];
  const float* W_ih = (const float*)d_in[4];
  const float* W_hh = (const float*)d_in[5];
  const float* b_ih = (const float*)d_in[6];
  const float* b_hh = (const float*)d_in[7];
  const float* W1   = (const float*)d_in[8];
  const float* b1   = (const float*)d_in[9];
  const float* W2   = (const float*)d_in[10];
  const float* b2   = (const float*)d_in[11];
  const float* W3   = (const float*)d_in[12];
  const float* b3   = (const float*)d_in[13];
  float* out = (float*)d_out;

  char* p = (char*)d_ws;
  auto alloc = [&](size_t bytes) {
    char* q = p;
    p += (bytes + 255) & ~(size_t)255;
    return q;
  };
  unsigned short* cbmB = (unsigned short*)alloc((size_t)BATCH*256*2);
  unsigned short* CW   = (unsigned short*)alloc((size_t)1024*256*2);
  unsigned short* WhhB = (unsigned short*)alloc((size_t)G3*256*2);
  unsigned short* W1aB = (unsigned short*)alloc((size_t)256*256*2);
  unsigned short* W2B  = (unsigned short*)alloc((size_t)256*256*2);
  unsigned short* W3pB = (unsigned short*)alloc((size_t)64*256*2);
  float* w0 = (float*)alloc((size_t)G3*4);
  float* gi = (float*)alloc((size_t)BATCH*G3*4);
  float* P1 = (float*)alloc((size_t)BATCH*256*4);
  float* ll = (float*)alloc((size_t)NROW*4);
  unsigned short* hs = (unsigned short*)alloc((size_t)NROW*HDIM*2);

  k_cvtall<<<6468, 256, 0, stream>>>(c, bv, mv, W_ih, W_hh, W1, W2, W3,
                                     cbmB, CW, WhhB, W1aB, W2B, W3pB, w0);
  k_pre<<<256, 512, 0, stream>>>(cbmB, CW, b_ih, b_hh, b1, gi, P1);
  k_gru<<<256, 256, 0, stream>>>(z, gi, WhhB, b_hh, w0, hs);
  k_mlp<<<NROW/128, 512, 0, stream>>>(hs, W1aB, P1, W2B, b2, W3pB, b3, z, ll);
  k_final<<<BATCH/4, 256, 0, stream>>>(bv, mv, ll, out);
}